// Round 6
// baseline (1226.394 us; speedup 1.0000x reference)
//
#include <hip/hip_runtime.h>

// y = alpha*(x @ Q^T) + bias; alpha = mean|W|; Q = clip(round(W/alpha),-1,1)
// x:(2,4096,4096) f32, W:(16384,4096) f32, bias:(16384) f32, out f32.
#define M_DIM 8192
#define N_DIM 16384
#define K_DIM 4096
#define NT 64  // K_DIM / 64

typedef unsigned short u16;
typedef unsigned int u32;
typedef __attribute__((ext_vector_type(8))) short bf16x8;
typedef __attribute__((ext_vector_type(8))) unsigned short u16x8;
typedef __attribute__((ext_vector_type(4))) float f32x4;

#define MFMA(a, b, c) __builtin_amdgcn_mfma_f32_16x16x32_bf16(a, b, c, 0, 0, 0)

__device__ __forceinline__ void gload16(const u16* g, u16* l) {
  __builtin_amdgcn_global_load_lds((const __attribute__((address_space(1))) void*)g,
                                   (__attribute__((address_space(3))) void*)l, 16, 0, 0);
}

// ---------------- alpha = mean(|W|), f64 two-pass reduction ----------------
__global__ void reduce_abs1(const float* __restrict__ w, double* __restrict__ partials) {
  const float4* w4 = (const float4*)w;
  size_t base = (size_t)blockIdx.x * 4096 + threadIdx.x;
  double s = 0.0;
#pragma unroll
  for (int i = 0; i < 16; ++i) {
    float4 v = w4[base + (size_t)i * 256];
    s += (double)fabsf(v.x); s += (double)fabsf(v.y);
    s += (double)fabsf(v.z); s += (double)fabsf(v.w);
  }
#pragma unroll
  for (int off = 32; off > 0; off >>= 1) s += __shfl_down(s, off, 64);
  __shared__ double red[4];
  int wv = threadIdx.x >> 6, lane = threadIdx.x & 63;
  if (lane == 0) red[wv] = s;
  __syncthreads();
  if (threadIdx.x == 0) partials[blockIdx.x] = (red[0] + red[1]) + (red[2] + red[3]);
}

__global__ void reduce_abs2(const double* __restrict__ partials,
                            double* __restrict__ alpha_d, float* __restrict__ alpha_f) {
  double s = 0.0;
  for (int i = threadIdx.x; i < 4096; i += 256) s += partials[i];
#pragma unroll
  for (int off = 32; off > 0; off >>= 1) s += __shfl_down(s, off, 64);
  __shared__ double red[4];
  int wv = threadIdx.x >> 6, lane = threadIdx.x & 63;
  if (lane == 0) red[wv] = s;
  __syncthreads();
  if (threadIdx.x == 0) {
    double total = (red[0] + red[1]) + (red[2] + red[3]);
    double a = total / (double)((long long)N_DIM * (long long)K_DIM);
    alpha_d[0] = a;
    alpha_f[0] = (float)a;
  }
}

// ---------------- W -> ternary Q stored as bf16 (+1/0/-1 exact) ----------------
__global__ void quant_w(const float* __restrict__ w, const double* __restrict__ alpha_d,
                        u16* __restrict__ q) {
  double inv = 1.0 / alpha_d[0];
  size_t i8 = (size_t)blockIdx.x * 256 + threadIdx.x;
  const float4* w4 = (const float4*)w;
  float4 v0 = w4[i8 * 2], v1 = w4[i8 * 2 + 1];
  float vv[8] = {v0.x, v0.y, v0.z, v0.w, v1.x, v1.y, v1.z, v1.w};
  u16x8 o;
#pragma unroll
  for (int j = 0; j < 8; ++j) {
    double r = rint((double)vv[j] * inv);
    u16 enc = 0;
    if (r >= 1.0) enc = 0x3F80u;
    else if (r <= -1.0) enc = 0xBF80u;
    o[j] = enc;
  }
  *((u16x8*)q + i8) = o;
}

// ---------------- x fp32 -> bf16 (RNE) ----------------
__global__ void conv_x(const float* __restrict__ x, u16* __restrict__ xb) {
  size_t i8 = (size_t)blockIdx.x * 256 + threadIdx.x;
  const float4* x4 = (const float4*)x;
  float4 v0 = x4[i8 * 2], v1 = x4[i8 * 2 + 1];
  float vv[8] = {v0.x, v0.y, v0.z, v0.w, v1.x, v1.y, v1.z, v1.w};
  u16x8 o;
#pragma unroll
  for (int j = 0; j < 8; ++j) {
    u32 u = __float_as_uint(vv[j]);
    u += 0x7FFFu + ((u >> 16) & 1u);
    o[j] = (u16)(u >> 16);
  }
  *((u16x8*)xb + i8) = o;
}

// ------- 256x256-tile bf16 GEMM, barrier-free intra-tile pipeline -------
// 512 threads = 8 waves (2M x 4N); per-wave 128x64 output = acc[8][4] f32x4.
// LDS: 2 tile-buffers x {A 256x64, B 256x64} bf16 = 128 KiB.
// Tile kt reads parity kt&1; stages write ONLY tile kt+1 (parity kt&1 ^ 1)
// -> staging never conflicts with current reads -> NO intra-tile barriers.
// Per tile: [8x global_load_lds (kt+1); 24 ds_read + 64 MFMA quadrant-ordered,
// compiler counted-lgkmcnt interleaves reads under MFMAs (wave ILP + 2w/SIMD
// TLP = MFMA||LDS overlap); vmcnt(0) (issued ~1 tile earlier: free); barrier].
// The single tile-end barrier stops fast waves from staging into the parity
// buffer slow waves still read. Depth-1 prefetch >> 900cy HBM latency.
__global__ __launch_bounds__(512, 2) void gemm256(
    const u16* __restrict__ A, const u16* __restrict__ Bq,
    const float* __restrict__ bias, const float* __restrict__ alpha_f,
    float* __restrict__ C) {
  __shared__ __align__(16) u16 Alds[2][2][128 * 64];  // [parity][half][r*64+k]
  __shared__ __align__(16) u16 Blds[2][2][128 * 64];

  const int t = threadIdx.x;
  const int wv = t >> 6, l = t & 63;
  const int wr = wv >> 2, wc = wv & 3;  // 2M x 4N wave grid
  const int lr = l & 15, lk = l >> 4;

  // XCD-bijective swizzle (2048 % 8 == 0) + 8(tm) x 64(tn) supertiles
  const int bid = blockIdx.x;
  const int wg = (bid & 7) * 256 + (bid >> 3);
  const int grp = wg >> 9, rem = wg & 511;
  const int tm = grp * 8 + (rem & 7);  // 0..31
  const int tn = rem >> 3;             // 0..63

  const u16* Ag = A + (size_t)tm * 256 * K_DIM;
  const u16* Bg = Bq + (size_t)tn * 256 * K_DIM;

  // staging source offsets (pre-swizzled global source, linear LDS dest)
  const int q0 = t, q1 = 512 + t;
  const int r0 = q0 >> 3, c0 = (q0 & 7) ^ (r0 & 7);
  const int r1 = q1 >> 3, c1 = (q1 & 7) ^ (r1 & 7);
  const size_t so0 = (size_t)r0 * K_DIM + c0 * 8;
  const size_t so1 = (size_t)r1 * K_DIM + c1 * 8;
  const int do0 = (wv * 64) * 8;          // u16 units (wave-uniform dest base)
  const int do1 = (512 + wv * 64) * 8;

  // Swizzled frag read bases (u16 units). For frag row r = sub*16 + lr:
  // r&7 == lr&7, so offset = sub*1024 + fb[ks];  sub*1024 folds to imm offset.
  const int fb0 = lr * 64 + ((lk ^ (lr & 7)) * 8);
  const int fb1 = lr * 64 + (((4 + lk) ^ (lr & 7)) * 8);
#define LDF(ptr, sub, ks) (*(const bf16x8*)((ptr) + (sub) * 1024 + ((ks) ? fb1 : fb0)))

  f32x4 acc[8][4];
#pragma unroll
  for (int mi = 0; mi < 8; ++mi)
#pragma unroll
    for (int ni = 0; ni < 4; ++ni)
      acc[mi][ni] = (f32x4){0.f, 0.f, 0.f, 0.f};

  // stage one half-tile H (2 x global_load_lds per wave); no-op past last tile
  auto stage = [&](int H) {
    int g = H >> 2;
    if (g < NT) {
      int sub = H & 3;  // 0:B0 1:B1 2:A0 3:A1
      const u16* src;
      u16* dst;
      if (sub < 2) { src = Bg + (size_t)sub * (128 * K_DIM); dst = &Blds[g & 1][sub][0]; }
      else         { src = Ag + (size_t)(sub - 2) * (128 * K_DIM); dst = &Alds[g & 1][sub - 2][0]; }
      src += g * 64;
      gload16(src + so0, dst + do0);
      gload16(src + so1, dst + do1);
    }
  };

  // one K-tile; par is a compile-time constant at each expansion
#define K_TILE(kt, par)                                                        \
  {                                                                            \
    const u16* Ar = &Alds[par][wr][0];                                         \
    const u16* Br = &Blds[par][wc >> 1][0] + (wc & 1) * 4096;                  \
    /* -- issue all 4 half-tile stages for tile kt+1 (opposite parity) -- */   \
    _Pragma("unroll") for (int h = 0; h < 4; ++h) stage(4 * ((kt) + 1) + h);   \
    __builtin_amdgcn_sched_barrier(0); /* keep stage-issues at tile top */     \
    bf16x8 bv[4][2], aA[4][2], aB[4][2];                                       \
    /* -- Q0: read A0-3(8)+B0-1(4); MFMA mi0-3 x ni0-1 -- */                   \
    _Pragma("unroll") for (int m = 0; m < 4; ++m) {                            \
      aA[m][0] = LDF(Ar, m, 0); aA[m][1] = LDF(Ar, m, 1);                      \
    }                                                                          \
    _Pragma("unroll") for (int ni = 0; ni < 2; ++ni) {                         \
      bv[ni][0] = LDF(Br, ni, 0); bv[ni][1] = LDF(Br, ni, 1);                  \
    }                                                                          \
    _Pragma("unroll") for (int ks = 0; ks < 2; ++ks)                           \
      _Pragma("unroll") for (int m = 0; m < 4; ++m)                            \
        _Pragma("unroll") for (int ni = 0; ni < 2; ++ni)                       \
          acc[m][ni] = MFMA(aA[m][ks], bv[ni][ks], acc[m][ni]);                \
    /* -- Q1: read B2-3(4); MFMA mi0-3 x ni2-3 -- */                           \
    _Pragma("unroll") for (int ni = 2; ni < 4; ++ni) {                         \
      bv[ni][0] = LDF(Br, ni, 0); bv[ni][1] = LDF(Br, ni, 1);                  \
    }                                                                          \
    _Pragma("unroll") for (int ks = 0; ks < 2; ++ks)                           \
      _Pragma("unroll") for (int m = 0; m < 4; ++m)                            \
        _Pragma("unroll") for (int ni = 2; ni < 4; ++ni)                       \
          acc[m][ni] = MFMA(aA[m][ks], bv[ni][ks], acc[m][ni]);                \
    /* -- Q2: read A4-7(8); MFMA mi4-7 x ni0-1 -- */                           \
    _Pragma("unroll") for (int m = 0; m < 4; ++m) {                            \
      aB[m][0] = LDF(Ar, 4 + m, 0); aB[m][1] = LDF(Ar, 4 + m, 1);              \
    }                                                                          \
    _Pragma("unroll") for (int ks = 0; ks < 2; ++ks)                           \
      _Pragma("unroll") for (int m = 0; m < 4; ++m)                            \
        _Pragma("unroll") for (int ni = 0; ni < 2; ++ni)                       \
          acc[4 + m][ni] = MFMA(aB[m][ks], bv[ni][ks], acc[4 + m][ni]);        \
    /* -- Q3: MFMA mi4-7 x ni2-3 (no reads) -- */                              \
    _Pragma("unroll") for (int ks = 0; ks < 2; ++ks)                           \
      _Pragma("unroll") for (int m = 0; m < 4; ++m)                            \
        _Pragma("unroll") for (int ni = 2; ni < 4; ++ni)                       \
          acc[4 + m][ni] = MFMA(aB[m][ks], bv[ni][ks], acc[4 + m][ni]);        \
    /* -- tile end: kt+1 stages landed (issued 1 tile ago); rendezvous -- */   \
    asm volatile("s_waitcnt vmcnt(0)" ::: "memory");                           \
    __builtin_amdgcn_s_barrier();                                              \
  }

  // prologue: stage tile 0 (parity 0); wait; barrier
#pragma unroll
  for (int H = 0; H < 4; ++H) stage(H);
  asm volatile("s_waitcnt vmcnt(0)" ::: "memory");
  __builtin_amdgcn_s_barrier();

  for (int kt2 = 0; kt2 < NT; kt2 += 2) {
    K_TILE(kt2, 0);
    K_TILE(kt2 + 1, 1);
  }
#undef K_TILE
#undef LDF

  // epilogue: y = alpha*acc + bias.  C/D: col=l&15, row=4*(l>>4)+j (m89-verified)
  const float alpha = alpha_f[0];
#pragma unroll
  for (int ni = 0; ni < 4; ++ni) {
    const int col = tn * 256 + wc * 64 + ni * 16 + lr;
    const float bs = bias[col];
#pragma unroll
    for (int mi = 0; mi < 8; ++mi) {
      const int row = tm * 256 + wr * 128 + mi * 16 + lk * 4;
      float* Cp = C + (size_t)row * N_DIM + col;
#pragma unroll
      for (int j = 0; j < 4; ++j)
        Cp[(size_t)j * N_DIM] = alpha * acc[mi][ni][j] + bs;
    }
  }
}

extern "C" void kernel_launch(void* const* d_in, const int* in_sizes, int n_in,
                              void* d_out, int out_size, void* d_ws, size_t ws_size,
                              hipStream_t stream) {
  const float* x = (const float*)d_in[0];
  const float* w = (const float*)d_in[1];
  const float* bias = (const float*)d_in[2];
  float* out = (float*)d_out;

  char* ws = (char*)d_ws;
  double* alpha_d = (double*)ws;
  float* alpha_f = (float*)(ws + 8);
  double* partials = (double*)(ws + 16);
  u16* xb = (u16*)(ws + 65536);                 // 64 MiB (M*K bf16)
  u16* qb = (u16*)(ws + 65536 + 67108864ULL);   // 128 MiB (N*K bf16)

  reduce_abs1<<<4096, 256, 0, stream>>>(w, partials);
  reduce_abs2<<<1, 256, 0, stream>>>(partials, alpha_d, alpha_f);
  quant_w<<<32768, 256, 0, stream>>>(w, alpha_d, qb);
  conv_x<<<16384, 256, 0, stream>>>(x, xb);
  gemm256<<<2048, 512, 0, stream>>>(xb, qb, bias, alpha_f, out);
}